// Round 11
// baseline (2484.107 us; speedup 1.0000x reference)
//
#include <hip/hip_runtime.h>

#define B_   128
#define S_   1024
#define I_   256
#define H_   512
#define L1_  256
#define O_   64

#define NGRP 8     // batch groups
#define WGPG 32    // workgroups per group (sync cohort)
#define MB   16    // batches per group
#define NH   16    // hidden units per WG
#define SX   8     // K-steps for X part (256/32)
#define SH   16    // K-steps for H part (512/32)

#define HB_UINTS_PER_BUF 32768   // 8 groups x 4096 uints (16KB fragment image per group)

typedef __attribute__((ext_vector_type(8))) short short8;
typedef __attribute__((ext_vector_type(4))) float f4;
typedef __attribute__((ext_vector_type(4))) unsigned u32x4;

__device__ __forceinline__ unsigned short f2bf(float x) {
  unsigned u = __builtin_bit_cast(unsigned, x);
  u += 0x7FFFu + ((u >> 16) & 1u);   // RNE
  return (unsigned short)(u >> 16);
}

__device__ __forceinline__ f4 mfma_bf16(short8 a, short8 b, f4 c) {
  asm("v_mfma_f32_16x16x32_bf16 %0, %1, %2, %0" : "+v"(c) : "v"(a), "v"(b));
  return c;
}

// pack 8 fp32 -> 8 bf16 (one 16B fragment chunk) via v_cvt_pk_bf16_f32
__device__ __forceinline__ void stage_chunk(unsigned short* dst, f4 a, f4 b) {
  unsigned d0, d1, d2, d3;
  asm("v_cvt_pk_bf16_f32 %0, %1, %2" : "=v"(d0) : "v"(a[0]), "v"(a[1]));
  asm("v_cvt_pk_bf16_f32 %0, %1, %2" : "=v"(d1) : "v"(a[2]), "v"(a[3]));
  asm("v_cvt_pk_bf16_f32 %0, %1, %2" : "=v"(d2) : "v"(b[0]), "v"(b[1]));
  asm("v_cvt_pk_bf16_f32 %0, %1, %2" : "=v"(d3) : "v"(b[2]), "v"(b[3]));
  u32x4 v = {d0, d1, d2, d3};
  *(u32x4*)dst = v;
}

// R11 = R8 skeleton + PER-WAVE system-scope flags posted BEFORE barrier D:
//   - R10 lesson: shared-line atomics serialize at the TCC (32 RMW producers +
//     32 RMW pollers regressed 8%). No atomics in the sync path.
//   - R7/R9 lesson: flag POLLS must be system scope (sc0-only polls hang on L1).
//   - Each wave drains its OWN H store (vmcnt 0) then lane0 posts its flag; the
//     LLC propagation overlaps barrier D instead of serializing behind it.
//   - Consumer polls 128 per-wave flags (2 coalesced loads/lane, same RT as 1).
//   - Barrier D retained solely for the AsX double-buffer WAR (R7 hang lesson).
// H DATA stays sc0/XCD-L2 when the cohort shares an XCD (proven: WRITE 140->9MB).
__global__ __launch_bounds__(256, 1)
void lstm_rec(const float* __restrict__ X,
              const float* __restrict__ Wxi, const float* __restrict__ Whi, const float* __restrict__ bi,
              const float* __restrict__ Wxf, const float* __restrict__ Whf, const float* __restrict__ bfp,
              const float* __restrict__ Wxo, const float* __restrict__ Who, const float* __restrict__ bop,
              const float* __restrict__ Wxc, const float* __restrict__ Whc, const float* __restrict__ bcp,
              float* __restrict__ out, unsigned* __restrict__ flags,
              unsigned* __restrict__ xslots, unsigned* __restrict__ Hbuf)
{
  // Fragment layout (verified R1-R10): element (k,col) -> lane=((k&31)>>3)*16+col, e=k&7.
  __shared__ unsigned short WhF[4][SH][64][8];  // 64 KB (dead after hoist)
  __shared__ unsigned short WxF[4][SX][64][8];  // 32 KB (dead after hoist; reused as AsX[2])
  __shared__ unsigned short AsH[SH][64][8];     // 16 KB  H A-fragments
  __shared__ float Psw[4][16][20];              // 5 KB   per-wave P transpose (padded)
  __shared__ int mode_s;

  const int tid  = threadIdx.x;
  const int lane = tid & 63;
  const int wv   = tid >> 6;
  const int g    = blockIdx.x & 7;  // batch group
  const int jg   = blockIdx.x >> 3; // hidden block 0..31
  const int j0   = jg * NH;
  const int b0   = g * MB;

  // ---- post our XCD id (s_getreg, m09 technique) ----
  unsigned xcc;
  asm volatile("s_getreg_b32 %0, hwreg(HW_REG_XCC_ID)" : "=s"(xcc));
  xcc &= 15u;
  if (tid == 0)
    __hip_atomic_store(xslots + g * 32 + jg, xcc + 1u,
                       __ATOMIC_RELAXED, __HIP_MEMORY_SCOPE_AGENT);

  // ---- issue X(t=0) loads; complete during weight packing ----
  const int idxA = tid, idxB = 256 + tid;
  const int sA = idxA >> 6, posA = idxA & 63;
  const int sB = idxB >> 6, posB = idxB & 63;
  const int offA = (sA * 64 + posA) * 8;     // ushort offset of 16B chunk in AsX buf
  const int offB = (sB * 64 + posB) * 8;
  const float* bpa = X + (size_t)(b0 + (posA & 15)) * S_ * I_ + (sA * 32 + (posA >> 4) * 8);
  const float* bpb = X + (size_t)(b0 + (posB & 15)) * S_ * I_ + (sB * 32 + (posB >> 4) * 8);
  f4 ra0 = *(const f4*)(bpa);
  f4 ra1 = *(const f4*)(bpa + 4);
  f4 rb0 = *(const f4*)(bpb);
  f4 rb1 = *(const f4*)(bpb + 4);

  const float* Whg[4] = {Whi, Whf, Who, Whc};
  const float* Wxg[4] = {Wxi, Wxf, Wxo, Wxc};
  const float* bgp[4] = {bi, bfp, bop, bcp};

  // ---- one-time: pack weight slices into LDS as bf16 B-fragments (per-gate) ----
  for (int gate = 0; gate < 4; ++gate) {
    const float* Wp = Whg[gate];
    for (int it = 0; it < 32; ++it) {
      int idx = it * 256 + tid;
      int k = idx >> 4, c = idx & 15;
      WhF[gate][k >> 5][((k & 31) >> 3) * 16 + c][k & 7] = f2bf(Wp[(size_t)k * H_ + j0 + c]);
    }
    const float* Xp = Wxg[gate];
    for (int it = 0; it < 16; ++it) {
      int idx = it * 256 + tid;
      int k = idx >> 4, c = idx & 15;
      WxF[gate][k >> 5][((k & 31) >> 3) * 16 + c][k & 7] = f2bf(Xp[(size_t)k * H_ + j0 + c]);
    }
  }
  if (tid == 0) mode_s = 0;
  __syncthreads();

  // ---- hoist B-fragments with INTERLEAVED-GATE column remap ----
  const int colL  = lane & 15;
  const int rgrpL = lane >> 4;
  const int gateL = colL >> 2;
  const int ccL   = colL & 3;
  short8 wx[SX], wh[SH];
  #pragma unroll
  for (int s = 0; s < SX; ++s)
    wx[s] = *(const short8*)&WxF[gateL][s][rgrpL * 16 + wv * 4 + ccL][0];
  #pragma unroll
  for (int s = 0; s < SH; ++s)
    wh[s] = *(const short8*)&WhF[gateL][s][rgrpL * 16 + wv * 4 + ccL][0];
  const float bv = bgp[gateL][j0 + wv * 4 + ccL];

  // ---- XCD handshake (wv0 computes, relay via LDS) ----
  if (wv == 0) {
    unsigned v;
    for (;;) {
      v = __hip_atomic_load(xslots + g * 32 + (lane & 31),
                            __ATOMIC_RELAXED, __HIP_MEMORY_SCOPE_AGENT);
      if (__all((int)(v != 0u))) break;
      __builtin_amdgcn_s_sleep(1);
    }
    unsigned f0 = (unsigned)__shfl((int)v, 0, 64);
    int same = __all((int)(v == f0));
    if (lane == 0) mode_s = same;
  }
  __syncthreads();            // hoist reads done before AsX alias writes; mode_s ready
  const bool l2m = (mode_s != 0);

  // ---- stage AsX[0] ----
  unsigned short* axbase = &WxF[0][0][0][0];   // alias: WxF is dead after hoist
  const int AXSTRIDE = SX * 64 * 8;
  stage_chunk(axbase + offA, ra0, ra1);
  stage_chunk(axbase + offB, rb0, rb1);
  __syncthreads();

  float Creg = 0.f;
  const int rowG = lane >> 2;          // gate-lane mapping: lane = row*4 + c
  const int cG   = lane & 3;
  const int jG   = j0 + wv * 4 + cG;
  const int dwH  = (((jG >> 5) * 64) + ((jG >> 3) & 3) * 16 + rowG) * 4 + ((jG & 7) >> 1);

  unsigned* gflags = flags + g * 128;  // 128 per-wave flags for this group
  const unsigned* fpA = gflags + lane;
  const unsigned* fpB = gflags + 64 + lane;
  unsigned* myflagp = gflags + jg * 4 + wv;

  for (int t = 0; t < S_; ++t) {
    const bool last = (t == S_ - 1);

    // ---- speculative flag pre-loads (system scope); FAIL-SAFE init 0 ----
    unsigned fa = 0u, fb = 0u;
    if (t > 0)
      asm volatile("global_load_dword %0, %2, off sc0 sc1\n\t"
                   "global_load_dword %1, %3, off sc0 sc1"
                   : "+v"(fa), "+v"(fb) : "v"(fpA), "v"(fpB) : "memory");

    // ---- X-part MFMAs (4 accumulators) ----
    f4 acc0 = {bv, bv, bv, bv};
    f4 acc1 = {0.f, 0.f, 0.f, 0.f};
    f4 acc2 = {0.f, 0.f, 0.f, 0.f};
    f4 acc3 = {0.f, 0.f, 0.f, 0.f};
    asm("s_nop 1" : "+v"(acc0), "+v"(acc1), "+v"(acc2), "+v"(acc3));
    const unsigned short* ax = axbase + (t & 1) * AXSTRIDE;
    #pragma unroll
    for (int s = 0; s < SX; ++s) {
      short8 a = *(const short8*)(ax + (s * 64 + lane) * 8);
      switch (s & 3) {
        case 0: acc0 = mfma_bf16(a, wx[s], acc0); break;
        case 1: acc1 = mfma_bf16(a, wx[s], acc1); break;
        case 2: acc2 = mfma_bf16(a, wx[s], acc2); break;
        default: acc3 = mfma_bf16(a, wx[s], acc3); break;
      }
    }

    // ---- wait for H_t (128 per-wave flags, data-dep tie + sched_barrier) ----
    if (t > 0) {
      asm volatile("s_waitcnt vmcnt(0)" : "+v"(fa), "+v"(fb) :: "memory");
      __builtin_amdgcn_sched_barrier(0);   // rule #18 fence
      if (!__all((int)((fa >= (unsigned)t) & (fb >= (unsigned)t)))) {
        for (;;) {
          unsigned v1, v2;
          asm volatile("global_load_dword %0, %2, off sc0 sc1\n\t"
                       "global_load_dword %1, %3, off sc0 sc1\n\t"
                       "s_waitcnt vmcnt(0)"
                       : "=v"(v1), "=v"(v2) : "v"(fpA), "v"(fpB) : "memory");
          if (__all((int)((v1 >= (unsigned)t) & (v2 >= (unsigned)t)))) break;
          __builtin_amdgcn_s_sleep(1);
        }
      }
      const u32x4* gp = (const u32x4*)(Hbuf + (size_t)(t & 1) * HB_UINTS_PER_BUF + g * 4096);
      u32x4 r0, r1, r2, r3;
      if (l2m) {
        asm volatile(
          "global_load_dwordx4 %0, %4, off sc0\n\t"
          "global_load_dwordx4 %1, %5, off sc0\n\t"
          "global_load_dwordx4 %2, %6, off sc0\n\t"
          "global_load_dwordx4 %3, %7, off sc0\n\t"
          "s_waitcnt vmcnt(0)"
          : "=&v"(r0), "=&v"(r1), "=&v"(r2), "=&v"(r3)
          : "v"(gp + tid), "v"(gp + tid + 256), "v"(gp + tid + 512), "v"(gp + tid + 768)
          : "memory");
      } else {
        asm volatile(
          "global_load_dwordx4 %0, %4, off sc0 sc1\n\t"
          "global_load_dwordx4 %1, %5, off sc0 sc1\n\t"
          "global_load_dwordx4 %2, %6, off sc0 sc1\n\t"
          "global_load_dwordx4 %3, %7, off sc0 sc1\n\t"
          "s_waitcnt vmcnt(0)"
          : "=&v"(r0), "=&v"(r1), "=&v"(r2), "=&v"(r3)
          : "v"(gp + tid), "v"(gp + tid + 256), "v"(gp + tid + 512), "v"(gp + tid + 768)
          : "memory");
      }
      u32x4* lp = (u32x4*)&AsH[0][0][0];
      lp[tid]       = r0;
      lp[tid + 256] = r1;
      lp[tid + 512] = r2;
      lp[tid + 768] = r3;
    }
    __syncthreads();   // B: AsH ready

    // ---- issue X(t+1) loads (compiler sinks waits to stage_chunk below) ----
    if (!last) {
      const float* pa  = bpa + (size_t)(t + 1) * I_;
      const float* pb2 = bpb + (size_t)(t + 1) * I_;
      ra0 = *(const f4*)(pa);
      ra1 = *(const f4*)(pa + 4);
      rb0 = *(const f4*)(pb2);
      rb1 = *(const f4*)(pb2 + 4);
    }

    // ---- H-part MFMAs (4 accumulators) ----
    if (t > 0) {
      #pragma unroll
      for (int s = 0; s < SH; ++s) {
        short8 a = *(const short8*)&AsH[s][lane][0];
        switch (s & 3) {
          case 0: acc0 = mfma_bf16(a, wh[s], acc0); break;
          case 1: acc1 = mfma_bf16(a, wh[s], acc1); break;
          case 2: acc2 = mfma_bf16(a, wh[s], acc2); break;
          default: acc3 = mfma_bf16(a, wh[s], acc3); break;
        }
      }
    }
    asm("s_nop 7\n\ts_nop 7" : "+v"(acc0), "+v"(acc1), "+v"(acc2), "+v"(acc3));
    f4 s01 = {acc0[0] + acc1[0], acc0[1] + acc1[1], acc0[2] + acc1[2], acc0[3] + acc1[3]};
    f4 s23 = {acc2[0] + acc3[0], acc2[1] + acc3[1], acc2[2] + acc3[2], acc2[3] + acc3[3]};
    f4 accs = {s01[0] + s23[0], s01[1] + s23[1], s01[2] + s23[2], s01[3] + s23[3]};

    // ---- same-wave transpose through LDS (NO barrier) ----
    *(f4*)&Psw[wv][colL][rgrpL * 4] = accs;
    asm volatile("s_waitcnt lgkmcnt(0)" ::: "memory");
    __builtin_amdgcn_sched_barrier(0);
    float pi = Psw[wv][cG][rowG];
    float pf = Psw[wv][4 + cG][rowG];
    float po = Psw[wv][8 + cG][rowG];
    float pc = Psw[wv][12 + cG][rowG];

    // ---- gates (fp32), C update ----
    float Ig = 1.f / (1.f + __expf(-pi));
    float Fg = 1.f / (1.f + __expf(-pf));
    float Og = 1.f / (1.f + __expf(-po));
    float Ct = 1.f - 2.f / (__expf(2.f * pc) + 1.f);          // tanh
    float Cn = Fg * Creg + Ig * Ct;
    Creg = Cn;
    float Hn = (1.f - 2.f / (__expf(2.f * Cn) + 1.f)) + Og;   // tanh(C) + O (addition!)

    if (!last) {
      // H pack (cvt_pk pair with lane partner) + store (l2m scope for DATA)
      float Hp = __shfl_xor(Hn, 1, 64);
      if ((cG & 1) == 0) {
        unsigned packed;
        asm("v_cvt_pk_bf16_f32 %0, %1, %2" : "=v"(packed) : "v"(Hn), "v"(Hp));
        unsigned* dst = Hbuf + (size_t)((t + 1) & 1) * HB_UINTS_PER_BUF + g * 4096 + dwH;
        if (l2m)
          asm volatile("global_store_dword %0, %1, off sc0" :: "v"(dst), "v"(packed) : "memory");
        else
          asm volatile("global_store_dword %0, %1, off sc0 sc1" :: "v"(dst), "v"(packed) : "memory");
      }
      // drain OWN H store, post this wave's flag (system scope) BEFORE barrier D
      asm volatile("s_waitcnt vmcnt(0)" ::: "memory");
      if (lane == 0) {
        unsigned tv = (unsigned)(t + 1);
        asm volatile("global_store_dword %0, %1, off sc0 sc1"
                     :: "v"(myflagp), "v"(tv) : "memory");
      }
      // stage X(t+1) into AsX[(t+1)&1] while the flag propagates
      unsigned short* axw = axbase + ((t + 1) & 1) * AXSTRIDE;
      stage_chunk(axw + offA, ra0, ra1);
      stage_chunk(axw + offB, rb0, rb1);

      __syncthreads();            // D: AsX double-buffer WAR protection (R7 lesson)
    } else {
      out[B_ * O_ + (size_t)(b0 + rowG) * H_ + jG] = Hn;            // Hf
      out[B_ * O_ + B_ * H_ + (size_t)(b0 + rowG) * H_ + jG] = Cn;  // Cf
    }
  }
}

// Output head: h1 = relu(Hf@W_o1+b_o1); out = softmax(h1@W_o2+b_o2). One WG per batch row.
__global__ __launch_bounds__(256, 1)
void lstm_head(const float* __restrict__ Hf,
               const float* __restrict__ Wo1, const float* __restrict__ bo1,
               const float* __restrict__ Wo2, const float* __restrict__ bo2,
               float* __restrict__ outp)
{
  __shared__ float hf[H_];
  __shared__ float h1[L1_];
  const int tid = threadIdx.x;
  const int b = blockIdx.x;
  hf[tid]       = Hf[(size_t)b * H_ + tid];
  hf[tid + 256] = Hf[(size_t)b * H_ + tid + 256];
  __syncthreads();
  float a = bo1[tid];
  #pragma unroll 8
  for (int k = 0; k < H_; ++k) a = fmaf(hf[k], Wo1[(size_t)k * L1_ + tid], a);
  h1[tid] = fmaxf(a, 0.f);
  __syncthreads();
  if (tid < O_) {
    float l = bo2[tid];
    #pragma unroll 8
    for (int j = 0; j < L1_; ++j) l = fmaf(h1[j], Wo2[(size_t)j * O_ + tid], l);
    float m = l;
    #pragma unroll
    for (int off = 32; off > 0; off >>= 1) m = fmaxf(m, __shfl_xor(m, off, 64));
    float e = __expf(l - m);
    float ssum = e;
    #pragma unroll
    for (int off = 32; off > 0; off >>= 1) ssum += __shfl_xor(ssum, off, 64);
    outp[(size_t)b * O_ + tid] = e / ssum;
  }
}

extern "C" void kernel_launch(void* const* d_in, const int* in_sizes, int n_in,
                              void* d_out, int out_size, void* d_ws, size_t ws_size,
                              hipStream_t stream) {
  (void)in_sizes; (void)n_in; (void)out_size; (void)ws_size;
  const float* X   = (const float*)d_in[0];
  const float* Wxi = (const float*)d_in[1];
  const float* Whi = (const float*)d_in[2];
  const float* bi  = (const float*)d_in[3];
  const float* Wxf = (const float*)d_in[4];
  const float* Whf = (const float*)d_in[5];
  const float* bfv = (const float*)d_in[6];
  const float* Wxo = (const float*)d_in[7];
  const float* Who = (const float*)d_in[8];
  const float* bo  = (const float*)d_in[9];
  const float* Wxc = (const float*)d_in[10];
  const float* Whc = (const float*)d_in[11];
  const float* bc  = (const float*)d_in[12];
  const float* Wo1 = (const float*)d_in[13];
  const float* bo1 = (const float*)d_in[14];
  const float* Wo2 = (const float*)d_in[15];
  const float* bo2 = (const float*)d_in[16];
  float* out = (float*)d_out;

  unsigned* flags  = (unsigned*)d_ws;                     // [0,4KB): per-WAVE step flags
  unsigned* xslots = (unsigned*)((char*)d_ws + 4096);     // [4KB,5KB): XCD slots
  unsigned* Hbuf   = (unsigned*)((char*)d_ws + 8192);     // 2 x 128KB fragment images

  (void)hipMemsetAsync(d_ws, 0, 8192, stream);  // reset flags + xslots every call
  hipLaunchKernelGGL(lstm_rec, dim3(NGRP * WGPG), dim3(256), 0, stream,
                     X, Wxi, Whi, bi, Wxf, Whf, bfv, Wxo, Who, bo, Wxc, Whc, bc,
                     out, flags, xslots, Hbuf);
  hipLaunchKernelGGL(lstm_head, dim3(B_), dim3(256), 0, stream,
                     out + B_ * O_, Wo1, bo1, Wo2, bo2, out);
}

// Round 12
// 2171.206 us; speedup vs baseline: 1.1441x; 1.1441x over previous
//
#include <hip/hip_runtime.h>

#define B_   128
#define S_   1024
#define I_   256
#define H_   512
#define L1_  256
#define O_   64

#define NGRP 8     // batch groups
#define WGPG 32    // workgroups per group (sync cohort)
#define MB   16    // batches per group
#define NH   16    // hidden units per WG
#define SX   8     // K-steps for X part (256/32)
#define SH   16    // K-steps for H part (512/32)

#define FSTRIDE 32               // flag stride in dwords: one 128B line per WG flag
#define HB_UINTS_PER_BUF 32768   // 8 groups x 4096 uints (16KB fragment image per group)

typedef __attribute__((ext_vector_type(8))) short short8;
typedef __attribute__((ext_vector_type(4))) float f4;
typedef __attribute__((ext_vector_type(4))) unsigned u32x4;

__device__ __forceinline__ unsigned short f2bf(float x) {
  unsigned u = __builtin_bit_cast(unsigned, x);
  u += 0x7FFFu + ((u >> 16) & 1u);   // RNE
  return (unsigned short)(u >> 16);
}

__device__ __forceinline__ f4 mfma_bf16(short8 a, short8 b, f4 c) {
  asm("v_mfma_f32_16x16x32_bf16 %0, %1, %2, %0" : "+v"(c) : "v"(a), "v"(b));
  return c;
}

// pack 8 fp32 -> 8 bf16 (one 16B fragment chunk) via v_cvt_pk_bf16_f32
__device__ __forceinline__ void stage_chunk(unsigned short* dst, f4 a, f4 b) {
  unsigned d0, d1, d2, d3;
  asm("v_cvt_pk_bf16_f32 %0, %1, %2" : "=v"(d0) : "v"(a[0]), "v"(a[1]));
  asm("v_cvt_pk_bf16_f32 %0, %1, %2" : "=v"(d1) : "v"(a[2]), "v"(a[3]));
  asm("v_cvt_pk_bf16_f32 %0, %1, %2" : "=v"(d2) : "v"(b[0]), "v"(b[1]));
  asm("v_cvt_pk_bf16_f32 %0, %1, %2" : "=v"(d3) : "v"(b[2]), "v"(b[3]));
  u32x4 v = {d0, d1, d2, d3};
  *(u32x4*)dst = v;
}

// R12 = R8 EXACT (best, 2164us) + ONE mechanism change:
//   flags spread to one 128B LINE PER WG (FSTRIDE=32 dwords) so the 32
//   near-simultaneous producer stores hit 32 LLC banks in parallel instead of
//   serializing on one line (R10/R11 lesson: flag path is LLC-contention-bound;
//   reduce serialization, never add traffic). Plus: no s_sleep in poll loops.
// Sync protocol, scopes, barriers, 2-acc MFMA: byte-identical to R8.
__global__ __launch_bounds__(256, 1)
void lstm_rec(const float* __restrict__ X,
              const float* __restrict__ Wxi, const float* __restrict__ Whi, const float* __restrict__ bi,
              const float* __restrict__ Wxf, const float* __restrict__ Whf, const float* __restrict__ bfp,
              const float* __restrict__ Wxo, const float* __restrict__ Who, const float* __restrict__ bop,
              const float* __restrict__ Wxc, const float* __restrict__ Whc, const float* __restrict__ bcp,
              float* __restrict__ out, unsigned* __restrict__ flags,
              unsigned* __restrict__ xslots, unsigned* __restrict__ Hbuf)
{
  // Fragment layout (verified R1-R11): element (k,col) -> lane=((k&31)>>3)*16+col, e=k&7.
  __shared__ unsigned short WhF[4][SH][64][8];  // 64 KB (dead after hoist)
  __shared__ unsigned short WxF[4][SX][64][8];  // 32 KB (dead after hoist; reused as AsX[2])
  __shared__ unsigned short AsH[SH][64][8];     // 16 KB  H A-fragments
  __shared__ float Psw[4][16][20];              // 5 KB   per-wave P transpose (padded)
  __shared__ int mode_s;

  const int tid  = threadIdx.x;
  const int lane = tid & 63;
  const int wv   = tid >> 6;
  const int g    = blockIdx.x & 7;  // batch group
  const int jg   = blockIdx.x >> 3; // hidden block 0..31
  const int j0   = jg * NH;
  const int b0   = g * MB;

  // ---- post our XCD id (s_getreg, m09 technique) ----
  unsigned xcc;
  asm volatile("s_getreg_b32 %0, hwreg(HW_REG_XCC_ID)" : "=s"(xcc));
  xcc &= 15u;
  if (tid == 0)
    __hip_atomic_store(xslots + g * 32 + jg, xcc + 1u,
                       __ATOMIC_RELAXED, __HIP_MEMORY_SCOPE_AGENT);

  // ---- issue X(t=0) loads; complete during weight packing ----
  const int idxA = tid, idxB = 256 + tid;
  const int sA = idxA >> 6, posA = idxA & 63;
  const int sB = idxB >> 6, posB = idxB & 63;
  const int offA = (sA * 64 + posA) * 8;     // ushort offset of 16B chunk in AsX buf
  const int offB = (sB * 64 + posB) * 8;
  const float* bpa = X + (size_t)(b0 + (posA & 15)) * S_ * I_ + (sA * 32 + (posA >> 4) * 8);
  const float* bpb = X + (size_t)(b0 + (posB & 15)) * S_ * I_ + (sB * 32 + (posB >> 4) * 8);
  f4 ra0 = *(const f4*)(bpa);
  f4 ra1 = *(const f4*)(bpa + 4);
  f4 rb0 = *(const f4*)(bpb);
  f4 rb1 = *(const f4*)(bpb + 4);

  const float* Whg[4] = {Whi, Whf, Who, Whc};
  const float* Wxg[4] = {Wxi, Wxf, Wxo, Wxc};
  const float* bgp[4] = {bi, bfp, bop, bcp};

  // ---- one-time: pack weight slices into LDS as bf16 B-fragments (per-gate) ----
  for (int gate = 0; gate < 4; ++gate) {
    const float* Wp = Whg[gate];
    for (int it = 0; it < 32; ++it) {
      int idx = it * 256 + tid;
      int k = idx >> 4, c = idx & 15;
      WhF[gate][k >> 5][((k & 31) >> 3) * 16 + c][k & 7] = f2bf(Wp[(size_t)k * H_ + j0 + c]);
    }
    const float* Xp = Wxg[gate];
    for (int it = 0; it < 16; ++it) {
      int idx = it * 256 + tid;
      int k = idx >> 4, c = idx & 15;
      WxF[gate][k >> 5][((k & 31) >> 3) * 16 + c][k & 7] = f2bf(Xp[(size_t)k * H_ + j0 + c]);
    }
  }
  if (tid == 0) mode_s = 0;
  __syncthreads();

  // ---- hoist B-fragments with INTERLEAVED-GATE column remap ----
  const int colL  = lane & 15;
  const int rgrpL = lane >> 4;
  const int gateL = colL >> 2;
  const int ccL   = colL & 3;
  short8 wx[SX], wh[SH];
  #pragma unroll
  for (int s = 0; s < SX; ++s)
    wx[s] = *(const short8*)&WxF[gateL][s][rgrpL * 16 + wv * 4 + ccL][0];
  #pragma unroll
  for (int s = 0; s < SH; ++s)
    wh[s] = *(const short8*)&WhF[gateL][s][rgrpL * 16 + wv * 4 + ccL][0];
  const float bv = bgp[gateL][j0 + wv * 4 + ccL];

  // ---- XCD handshake (wv0 computes, relay via LDS) ----
  if (wv == 0) {
    unsigned v;
    for (;;) {
      v = __hip_atomic_load(xslots + g * 32 + (lane & 31),
                            __ATOMIC_RELAXED, __HIP_MEMORY_SCOPE_AGENT);
      if (__all((int)(v != 0u))) break;
      __builtin_amdgcn_s_sleep(1);
    }
    unsigned f0 = (unsigned)__shfl((int)v, 0, 64);
    int same = __all((int)(v == f0));
    if (lane == 0) mode_s = same;
  }
  __syncthreads();            // hoist reads done before AsX alias writes; mode_s ready
  const bool l2m = (mode_s != 0);

  // ---- stage AsX[0] ----
  unsigned short* axbase = &WxF[0][0][0][0];   // alias: WxF is dead after hoist
  const int AXSTRIDE = SX * 64 * 8;
  stage_chunk(axbase + offA, ra0, ra1);
  stage_chunk(axbase + offB, rb0, rb1);
  __syncthreads();

  float Creg = 0.f;
  const int rowG = lane >> 2;          // gate-lane mapping: lane = row*4 + c
  const int cG   = lane & 3;
  const int jG   = j0 + wv * 4 + cG;
  const int dwH  = (((jG >> 5) * 64) + ((jG >> 3) & 3) * 16 + rowG) * 4 + ((jG & 7) >> 1);

  unsigned* myflags = flags + (size_t)g * 32 * FSTRIDE;   // 32 lines per group
  const unsigned* fp0 = myflags + (size_t)(lane & 31) * FSTRIDE;
  unsigned* myflagp = myflags + (size_t)jg * FSTRIDE;

  for (int t = 0; t < S_; ++t) {
    const bool last = (t == S_ - 1);

    // ---- speculative flag pre-load (all waves); FAIL-SAFE init 0 ----
    unsigned fpre = 0u;
    if (t > 0)
      asm volatile("global_load_dword %0, %1, off sc0 sc1"
                   : "+v"(fpre) : "v"(fp0) : "memory");

    // ---- X-part MFMAs (2 accumulators, R8-exact) ----
    f4 acc0 = {bv, bv, bv, bv};
    f4 acc1 = {0.f, 0.f, 0.f, 0.f};
    asm("s_nop 1" : "+v"(acc0));
    asm("s_nop 1" : "+v"(acc1));
    const unsigned short* ax = axbase + (t & 1) * AXSTRIDE;
    #pragma unroll
    for (int s = 0; s < SX; ++s) {
      short8 a = *(const short8*)(ax + (s * 64 + lane) * 8);
      if (s & 1) acc1 = mfma_bf16(a, wx[s], acc1);
      else       acc0 = mfma_bf16(a, wx[s], acc0);
    }

    // ---- wait for H_t (data-dep tie + sched_barrier, R5-proven), load H image ----
    if (t > 0) {
      asm volatile("s_waitcnt vmcnt(0)" : "+v"(fpre) :: "memory");
      __builtin_amdgcn_sched_barrier(0);   // rule #18 fence
      if (!__all((int)(fpre >= (unsigned)t))) {
        for (;;) {
          unsigned v = __hip_atomic_load(fp0, __ATOMIC_RELAXED, __HIP_MEMORY_SCOPE_AGENT);
          if (__all((int)(v >= (unsigned)t))) break;
          // busy spin: 1 WG/CU, nothing to yield to
        }
      }
      const u32x4* gp = (const u32x4*)(Hbuf + (size_t)(t & 1) * HB_UINTS_PER_BUF + g * 4096);
      u32x4 r0, r1, r2, r3;
      if (l2m) {
        asm volatile(
          "global_load_dwordx4 %0, %4, off sc0\n\t"
          "global_load_dwordx4 %1, %5, off sc0\n\t"
          "global_load_dwordx4 %2, %6, off sc0\n\t"
          "global_load_dwordx4 %3, %7, off sc0\n\t"
          "s_waitcnt vmcnt(0)"
          : "=&v"(r0), "=&v"(r1), "=&v"(r2), "=&v"(r3)
          : "v"(gp + tid), "v"(gp + tid + 256), "v"(gp + tid + 512), "v"(gp + tid + 768)
          : "memory");
      } else {
        asm volatile(
          "global_load_dwordx4 %0, %4, off sc0 sc1\n\t"
          "global_load_dwordx4 %1, %5, off sc0 sc1\n\t"
          "global_load_dwordx4 %2, %6, off sc0 sc1\n\t"
          "global_load_dwordx4 %3, %7, off sc0 sc1\n\t"
          "s_waitcnt vmcnt(0)"
          : "=&v"(r0), "=&v"(r1), "=&v"(r2), "=&v"(r3)
          : "v"(gp + tid), "v"(gp + tid + 256), "v"(gp + tid + 512), "v"(gp + tid + 768)
          : "memory");
      }
      u32x4* lp = (u32x4*)&AsH[0][0][0];
      lp[tid]       = r0;
      lp[tid + 256] = r1;
      lp[tid + 512] = r2;
      lp[tid + 768] = r3;
    }
    __syncthreads();   // B: AsH ready

    // ---- issue X(t+1) loads (compiler sinks the waits to stage_chunk below) ----
    if (!last) {
      const float* pa  = bpa + (size_t)(t + 1) * I_;
      const float* pb2 = bpb + (size_t)(t + 1) * I_;
      ra0 = *(const f4*)(pa);
      ra1 = *(const f4*)(pa + 4);
      rb0 = *(const f4*)(pb2);
      rb1 = *(const f4*)(pb2 + 4);
    }

    // ---- H-part MFMAs ----
    if (t > 0) {
      #pragma unroll
      for (int s = 0; s < SH; ++s) {
        short8 a = *(const short8*)&AsH[s][lane][0];
        if (s & 1) acc1 = mfma_bf16(a, wh[s], acc1);
        else       acc0 = mfma_bf16(a, wh[s], acc0);
      }
    }
    asm("s_nop 7" : "+v"(acc0));
    asm("s_nop 7" : "+v"(acc1));
    f4 accs = {acc0[0] + acc1[0], acc0[1] + acc1[1], acc0[2] + acc1[2], acc0[3] + acc1[3]};

    // ---- same-wave transpose through LDS (NO barrier) ----
    *(f4*)&Psw[wv][colL][rgrpL * 4] = accs;
    asm volatile("s_waitcnt lgkmcnt(0)" ::: "memory");
    __builtin_amdgcn_sched_barrier(0);
    float pi = Psw[wv][cG][rowG];
    float pf = Psw[wv][4 + cG][rowG];
    float po = Psw[wv][8 + cG][rowG];
    float pc = Psw[wv][12 + cG][rowG];

    // ---- gates (fp32), C update ----
    float Ig = 1.f / (1.f + __expf(-pi));
    float Fg = 1.f / (1.f + __expf(-pf));
    float Og = 1.f / (1.f + __expf(-po));
    float Ct = 1.f - 2.f / (__expf(2.f * pc) + 1.f);          // tanh
    float Cn = Fg * Creg + Ig * Ct;
    Creg = Cn;
    float Hn = (1.f - 2.f / (__expf(2.f * Cn) + 1.f)) + Og;   // tanh(C) + O (addition!)

    if (!last) {
      // stage X(t+1) into AsX[(t+1)&1] (compiler waits the X loads here)
      unsigned short* axw = axbase + ((t + 1) & 1) * AXSTRIDE;
      stage_chunk(axw + offA, ra0, ra1);
      stage_chunk(axw + offB, rb0, rb1);

      // H pack (cvt_pk pair with lane partner) + store
      float Hp = __shfl_xor(Hn, 1, 64);
      if ((cG & 1) == 0) {
        unsigned packed;
        asm("v_cvt_pk_bf16_f32 %0, %1, %2" : "=v"(packed) : "v"(Hn), "v"(Hp));
        unsigned* dst = Hbuf + (size_t)((t + 1) & 1) * HB_UINTS_PER_BUF + g * 4096 + dwH;
        if (l2m)
          asm volatile("global_store_dword %0, %1, off sc0" :: "v"(dst), "v"(packed) : "memory");
        else
          asm volatile("global_store_dword %0, %1, off sc0 sc1" :: "v"(dst), "v"(packed) : "memory");
      }
      __syncthreads();            // D: ALL waves' H stores + AsX writes drained (R8 protocol)
      if (tid == 0)
        __hip_atomic_store(myflagp, (unsigned)(t + 1),
                           __ATOMIC_RELAXED, __HIP_MEMORY_SCOPE_AGENT);
    } else {
      out[B_ * O_ + (size_t)(b0 + rowG) * H_ + jG] = Hn;            // Hf
      out[B_ * O_ + B_ * H_ + (size_t)(b0 + rowG) * H_ + jG] = Cn;  // Cf
    }
  }
}

// Output head: h1 = relu(Hf@W_o1+b_o1); out = softmax(h1@W_o2+b_o2). One WG per batch row.
__global__ __launch_bounds__(256, 1)
void lstm_head(const float* __restrict__ Hf,
               const float* __restrict__ Wo1, const float* __restrict__ bo1,
               const float* __restrict__ Wo2, const float* __restrict__ bo2,
               float* __restrict__ outp)
{
  __shared__ float hf[H_];
  __shared__ float h1[L1_];
  const int tid = threadIdx.x;
  const int b = blockIdx.x;
  hf[tid]       = Hf[(size_t)b * H_ + tid];
  hf[tid + 256] = Hf[(size_t)b * H_ + tid + 256];
  __syncthreads();
  float a = bo1[tid];
  #pragma unroll 8
  for (int k = 0; k < H_; ++k) a = fmaf(hf[k], Wo1[(size_t)k * L1_ + tid], a);
  h1[tid] = fmaxf(a, 0.f);
  __syncthreads();
  if (tid < O_) {
    float l = bo2[tid];
    #pragma unroll 8
    for (int j = 0; j < L1_; ++j) l = fmaf(h1[j], Wo2[(size_t)j * O_ + tid], l);
    float m = l;
    #pragma unroll
    for (int off = 32; off > 0; off >>= 1) m = fmaxf(m, __shfl_xor(m, off, 64));
    float e = __expf(l - m);
    float ssum = e;
    #pragma unroll
    for (int off = 32; off > 0; off >>= 1) ssum += __shfl_xor(ssum, off, 64);
    outp[(size_t)b * O_ + tid] = e / ssum;
  }
}

extern "C" void kernel_launch(void* const* d_in, const int* in_sizes, int n_in,
                              void* d_out, int out_size, void* d_ws, size_t ws_size,
                              hipStream_t stream) {
  (void)in_sizes; (void)n_in; (void)out_size; (void)ws_size;
  const float* X   = (const float*)d_in[0];
  const float* Wxi = (const float*)d_in[1];
  const float* Whi = (const float*)d_in[2];
  const float* bi  = (const float*)d_in[3];
  const float* Wxf = (const float*)d_in[4];
  const float* Whf = (const float*)d_in[5];
  const float* bfv = (const float*)d_in[6];
  const float* Wxo = (const float*)d_in[7];
  const float* Who = (const float*)d_in[8];
  const float* bo  = (const float*)d_in[9];
  const float* Wxc = (const float*)d_in[10];
  const float* Whc = (const float*)d_in[11];
  const float* bc  = (const float*)d_in[12];
  const float* Wo1 = (const float*)d_in[13];
  const float* bo1 = (const float*)d_in[14];
  const float* Wo2 = (const float*)d_in[15];
  const float* bo2 = (const float*)d_in[16];
  float* out = (float*)d_out;

  unsigned* flags  = (unsigned*)d_ws;                     // [0,32KB): 1 line per WG flag
  unsigned* xslots = (unsigned*)((char*)d_ws + 32768);    // [32KB,33KB): XCD slots
  unsigned* Hbuf   = (unsigned*)((char*)d_ws + 36864);    // 2 x 128KB fragment images

  (void)hipMemsetAsync(d_ws, 0, 36864, stream);  // reset flags + xslots every call
  hipLaunchKernelGGL(lstm_rec, dim3(NGRP * WGPG), dim3(256), 0, stream,
                     X, Wxi, Whi, bi, Wxf, Whf, bfv, Wxo, Who, bo, Wxc, Whc, bc,
                     out, flags, xslots, Hbuf);
  hipLaunchKernelGGL(lstm_head, dim3(B_), dim3(256), 0, stream,
                     out + B_ * O_, Wo1, bo1, Wo2, bo2, out);
}